// Round 1
// baseline (1204.877 us; speedup 1.0000x reference)
//
#include <hip/hip_runtime.h>

// Problem constants (fixed by reference):
//   B=8, C=32, H=W=32 -> Ho=Wo=16, N=Ho*Wo=256, HW=H*W=1024
//   mu_in   : [B,C,H,W]        f32
//   Sigma_in: [B,C,HW,HW]      f32
//   out     : mu_out [B,C,Ho,Wo] (65536 f32)  ++  Sigma_out [B,C,N,N] (16777216 f32)

#define BC    256        // B*C
#define H     32
#define W     32
#define HO    16
#define WO    16
#define NPOOL 256        // HO*WO
#define HW    1024       // H*W

// Kernel 1: 2x2 max pool with argmax flat indices (unchanged - ~5us, negligible).
// grid = BC blocks, 256 threads; thread t handles pooled pixel n=t of image bc.
__global__ void pool_idx_kernel(const float* __restrict__ mu_in,
                                float* __restrict__ mu_out,
                                int* __restrict__ idx_ws) {
    const int bc = blockIdx.x;          // 0..255
    const int n  = threadIdx.x;         // 0..255
    const int i  = n >> 4;              // pooled row 0..15
    const int j  = n & 15;              // pooled col 0..15

    const float* img = mu_in + (size_t)bc * (H * W);
    const int r0 = 2 * i, c0 = 2 * j;

    // window order w = kh*2 + kw (matches jnp.argmax first-occurrence; strict > keeps first)
    float v0 = img[(r0    ) * W + c0    ];
    float v1 = img[(r0    ) * W + c0 + 1];
    float v2 = img[(r0 + 1) * W + c0    ];
    float v3 = img[(r0 + 1) * W + c0 + 1];

    float best = v0; int w = 0;
    if (v1 > best) { best = v1; w = 1; }
    if (v2 > best) { best = v2; w = 2; }
    if (v3 > best) { best = v3; w = 3; }

    const int row = r0 + (w >> 1);
    const int col = c0 + (w & 1);
    const int flat = row * W + col;     // 0..1023

    mu_out[(size_t)bc * NPOOL + n] = best;
    idx_ws[bc * NPOOL + n] = flat;
}

// Kernel 2: double gather, restructured for coalescing.
//
// Old version: per-lane scattered 4B global loads -> transaction-rate bound (~9% of BW).
// New version: wave-per-output-row. Read the FULL source row r=idx[i] (1024 f32 = 4 KiB)
// with coalesced float4 loads into a wave-private LDS buffer, column-gather from LDS
// (LDS tolerates scatter), write output row as coalesced float4.
// HBM traffic identical (every 64B line of a selected row holds ~4 needed floats anyway),
// but now issued as wide coalesced transactions -> BW-bound.
//
// grid = BC * 8 = 2048 blocks, 256 threads (4 waves). Each block: 32 output rows
// (8 per wave, sequential). No block-wide barrier in the row loop (wave-private buffers).
// LDS: 1 KiB idx + 4 * 4 KiB row buffers = 17 KiB -> 8 blocks/CU (139 KiB), 32 waves/CU.
#define ROWS_PER_WAVE   8
#define WAVES_PER_BLOCK 4
#define ROWS_PER_BLOCK  (ROWS_PER_WAVE * WAVES_PER_BLOCK)   // 32
#define BLOCKS_PER_BC   (NPOOL / ROWS_PER_BLOCK)            // 8

__global__ __launch_bounds__(256, 8)
void sigma_gather_kernel(const float* __restrict__ Sigma_in,
                         const int* __restrict__ idx_ws,
                         float* __restrict__ Sigma_out) {
    __shared__ int   s_idx[NPOOL];
    __shared__ float s_row[WAVES_PER_BLOCK][HW];

    const int blk   = blockIdx.x;
    const int bc    = blk >> 3;         // / BLOCKS_PER_BC
    const int chunk = blk & 7;
    const int tid   = threadIdx.x;
    const int wave  = tid >> 6;
    const int lane  = tid & 63;

    s_idx[tid] = idx_ws[bc * NPOOL + tid];
    __syncthreads();

    const float* Sbase = Sigma_in  + (size_t)bc * (HW * HW);
    float*       Obase = Sigma_out + (size_t)bc * (NPOOL * NPOOL);

    // This lane's 4 output columns (j = 4*lane .. 4*lane+3) -> source columns. Hoisted.
    const int j0 = 4 * lane;
    const int c0 = s_idx[j0 + 0];
    const int c1 = s_idx[j0 + 1];
    const int c2 = s_idx[j0 + 2];
    const int c3 = s_idx[j0 + 3];

    const int ibase = chunk * ROWS_PER_BLOCK + wave * ROWS_PER_WAVE;
    float* rowbuf = s_row[wave];        // wave-private: no __syncthreads in the loop

    #pragma unroll 2
    for (int t = 0; t < ROWS_PER_WAVE; ++t) {
        const int i = ibase + t;        // output row
        const int r = s_idx[i];         // source row (wave-uniform LDS broadcast)

        // Coalesced full-row read: 64 lanes x 4 float4 = 4 KiB.
        const float4* src4 = (const float4*)(Sbase + (size_t)r * HW);
        float4 v0 = src4[lane      ];
        float4 v1 = src4[lane +  64];
        float4 v2 = src4[lane + 128];
        float4 v3 = src4[lane + 192];

        float4* rb4 = (float4*)rowbuf;
        rb4[lane      ] = v0;
        rb4[lane +  64] = v1;
        rb4[lane + 128] = v2;
        rb4[lane + 192] = v3;
        // (within-wave LDS write->read ordering handled by compiler waitcnts;
        //  no cross-wave sharing of rowbuf)

        // Column gather from LDS + coalesced float4 store.
        float4 o;
        o.x = rowbuf[c0];
        o.y = rowbuf[c1];
        o.z = rowbuf[c2];
        o.w = rowbuf[c3];
        ((float4*)(Obase + (size_t)i * NPOOL))[lane] = o;
    }
}

extern "C" void kernel_launch(void* const* d_in, const int* in_sizes, int n_in,
                              void* d_out, int out_size, void* d_ws, size_t ws_size,
                              hipStream_t stream) {
    const float* mu_in    = (const float*)d_in[0];
    const float* Sigma_in = (const float*)d_in[1];

    float* mu_out    = (float*)d_out;                 // 65536 floats
    float* Sigma_out = (float*)d_out + BC * NPOOL;    // 16777216 floats
    int*   idx_ws    = (int*)d_ws;                    // 256*256 ints = 256 KiB

    pool_idx_kernel<<<BC, NPOOL, 0, stream>>>(mu_in, mu_out, idx_ws);
    sigma_gather_kernel<<<BC * BLOCKS_PER_BC, 256, 0, stream>>>(Sigma_in, idx_ws, Sigma_out);
}